// Round 4
// baseline (249.843 us; speedup 1.0000x reference)
//
#include <hip/hip_runtime.h>
#include <math.h>

#define BB 4
#define C 256
#define H 64
#define W 64
#define HW 4096
#define HO 128
#define WO 128
#define HWO 16384
#define EMB 64

typedef __bf16 bf16x8 __attribute__((ext_vector_type(8)));
typedef __bf16 bf16x4 __attribute__((ext_vector_type(4)));
typedef float  f32x4  __attribute__((ext_vector_type(4)));

__device__ __forceinline__ f32x4 mfma16(bf16x8 a, bf16x8 b, f32x4 c) {
    return __builtin_amdgcn_mfma_f32_16x16x32_bf16(a, b, c, 0, 0, 0);
}

// ---------------------------------------------------------------------------
// K1: weight tables (bf16)
//   wbf_cen: [e][c] (=w_cen layout, cast)
//   wdec5:   [5mt][16m][256c]; mt<4 = w_cde; mt=4 row0 = w_gate, rest 0
//   w3:      [tap9][mt2][16m][64e], rows m>=25 zeroed
// ---------------------------------------------------------------------------
__global__ void k_prep2(const float* __restrict__ w_cen,
                        const float* __restrict__ w_cde,
                        const float* __restrict__ w_gate,
                        const float* __restrict__ w_ce,
                        __bf16* __restrict__ wbf_cen,
                        __bf16* __restrict__ wdec5,
                        __bf16* __restrict__ w3) {
    for (int idx = blockIdx.x * blockDim.x + threadIdx.x; idx < 16384;
         idx += gridDim.x * blockDim.x)
        wbf_cen[idx] = (__bf16)w_cen[idx];
    for (int idx = blockIdx.x * blockDim.x + threadIdx.x; idx < 20480;
         idx += gridDim.x * blockDim.x) {
        int c = idx & 255, m = (idx >> 8) & 15;
        float v;
        if (idx < 16384) v = w_cde[idx];
        else             v = (m == 0) ? w_gate[c] : 0.f;
        wdec5[idx] = (__bf16)v;
    }
    for (int idx = blockIdx.x * blockDim.x + threadIdx.x; idx < 18432;
         idx += gridDim.x * blockDim.x) {
        int e = idx & 63;
        int m = (idx >> 6) & 15;
        int mt = (idx >> 10) & 1;
        int tap = idx >> 11;
        int q = mt * 16 + m;
        int dy = tap / 3, dx = tap % 3;
        w3[idx] = (q < 25) ? (__bf16)w_ce[((q * EMB + e) * 3 + dy) * 3 + dx]
                           : (__bf16)0.0f;
    }
}

// ---------------------------------------------------------------------------
// K2: MFMA GEMM Y[px][e] = Wt[e][c]·X[c][px], double-buffered LDS, 128-px
//   tiles. blocks [0,512): enc (+b_cen); [512,640): dec (+gate row)
// ---------------------------------------------------------------------------
__global__ __launch_bounds__(256) void k_gemm1(
        const float* __restrict__ en, const float* __restrict__ de,
        const __bf16* __restrict__ wbf_cen, const __bf16* __restrict__ wdec5,
        const float* __restrict__ b_cen, const float* __restrict__ b_gate,
        __bf16* __restrict__ enc_t, __bf16* __restrict__ dec_t,
        float* __restrict__ gate_lr) {
    __shared__ float xs[2][32][136];              // 34816 B
    int t = threadIdx.x;
    int w = t >> 6, lane = t & 63;
    int n = lane & 15, q = lane >> 4;
    bool isenc = blockIdx.x < 512;
    const float* X; const __bf16* Wt; __bf16* Y; int plane, px0, b;
    if (isenc) {
        int blk = blockIdx.x; b = blk >> 7; px0 = (blk & 127) << 7;
        X = en + (size_t)b * C * HWO; plane = HWO; Wt = wbf_cen;
        Y = enc_t + (size_t)b * HWO * EMB;
    } else {
        int blk = blockIdx.x - 512; b = blk >> 5; px0 = (blk & 31) << 7;
        X = de + (size_t)b * C * HW; plane = HW; Wt = wdec5;
        Y = dec_t + (size_t)b * HW * EMB;
    }
    int scc = t >> 5;                 // staging c row 0..7
    int sp4 = (t & 31) << 2;          // staging px offset
    float4 pre[4];
    #pragma unroll
    for (int i = 0; i < 4; i++)
        pre[i] = *(const float4*)(X + (size_t)(i * 8 + scc) * plane + px0 + sp4);
    #pragma unroll
    for (int i = 0; i < 4; i++)
        *(float4*)(&xs[0][i * 8 + scc][sp4]) = pre[i];
    __syncthreads();

    f32x4 acc[4][2] = {};
    f32x4 accg[2] = {};
    for (int kc = 0; kc < 8; kc++) {
        int cur = kc & 1;
        if (kc < 7) {
            int c1 = (kc + 1) * 32;
            #pragma unroll
            for (int i = 0; i < 4; i++)
                pre[i] = *(const float4*)(X + (size_t)(c1 + i * 8 + scc) * plane
                                          + px0 + sp4);
        }
        int c0 = kc * 32;
        bf16x8 af[4];
        #pragma unroll
        for (int mt = 0; mt < 4; mt++)
            af[mt] = *(const bf16x8*)(Wt + (size_t)(mt * 16 + n) * C + c0 + q * 8);
        bf16x8 bv[2];
        #pragma unroll
        for (int nt = 0; nt < 2; nt++) {
            int px = w * 32 + nt * 16 + n;
            #pragma unroll
            for (int j = 0; j < 8; j++)
                bv[nt][j] = (__bf16)xs[cur][q * 8 + j][px];
        }
        #pragma unroll
        for (int mt = 0; mt < 4; mt++) {
            acc[mt][0] = mfma16(af[mt], bv[0], acc[mt][0]);
            acc[mt][1] = mfma16(af[mt], bv[1], acc[mt][1]);
        }
        if (!isenc) {
            bf16x8 ag = *(const bf16x8*)(Wt + (size_t)(64 + n) * C + c0 + q * 8);
            accg[0] = mfma16(ag, bv[0], accg[0]);
            accg[1] = mfma16(ag, bv[1], accg[1]);
        }
        if (kc < 7) {
            #pragma unroll
            for (int i = 0; i < 4; i++)
                *(float4*)(&xs[cur ^ 1][i * 8 + scc][sp4]) = pre[i];
        }
        __syncthreads();
    }

    #pragma unroll
    for (int nt = 0; nt < 2; nt++) {
        int gpx = px0 + w * 32 + nt * 16 + n;
        #pragma unroll
        for (int mt = 0; mt < 4; mt++) {
            int e0 = mt * 16 + q * 4;
            bf16x4 ov;
            #pragma unroll
            for (int r = 0; r < 4; r++) {
                float bias = isenc ? b_cen[e0 + r] : 0.f;
                ov[r] = (__bf16)(acc[mt][nt][r] + bias);
            }
            *(bf16x4*)(Y + (size_t)gpx * EMB + e0) = ov;
        }
        if (!isenc && q == 0)
            gate_lr[b * HW + gpx] =
                1.f / (1.f + __expf(-(accg[nt][0] + b_gate[0])));
    }
}

// ---------------------------------------------------------------------------
// K3: 3x3 conv 64->25 via MFMA; 3 input rows staged in LDS in fragment order
//     (zero-padded halo). blocks [0,1024): enc_t->tmp1; [1024,1280): dec_t->tmp2
// ---------------------------------------------------------------------------
__global__ __launch_bounds__(256) void k_conv3m(
        const __bf16* __restrict__ enc_t, const __bf16* __restrict__ dec_t,
        const __bf16* __restrict__ w3, const float* __restrict__ b_ce,
        float* __restrict__ tmp1, float* __restrict__ tmp2) {
    __shared__ __bf16 sfr[8 * 3 * 66 * 8];        // 25.3 KB
    int t = threadIdx.x;
    int w = t >> 6, lane = t & 63;
    int n = lane & 15, q = lane >> 4;
    bool hi = blockIdx.x < 1024;
    const __bf16* src; float* dst; int b, y, width, plane, x0;
    if (hi) {
        int blk = blockIdx.x; b = blk >> 8; int r = blk & 255;
        y = r >> 1; x0 = (r & 1) * 64;
        width = WO; plane = HWO;
        src = enc_t + (size_t)b * HWO * EMB; dst = tmp1;
    } else {
        int blk = blockIdx.x - 1024; b = blk >> 6; y = blk & 63; x0 = 0;
        width = W; plane = HW;
        src = dec_t + (size_t)b * HW * EMB; dst = tmp2;
    }
    bf16x8 zf;
    #pragma unroll
    for (int j = 0; j < 8; j++) zf[j] = (__bf16)0.0f;
    for (int idx = t; idx < 1584; idx += 256) {
        int f = idx & 7;
        int rem = idx >> 3;
        int xloc = rem % 66, row = rem / 66;
        int yy = y + row - 1, xg = x0 - 1 + xloc;
        bf16x8 v = zf;
        if ((unsigned)yy < (unsigned)width && (unsigned)xg < (unsigned)width)
            v = *(const bf16x8*)(src + ((size_t)yy * width + xg) * EMB + f * 8);
        *(bf16x8*)(sfr + (((f * 3) + row) * 66 + xloc) * 8) = v;
    }
    __syncthreads();

    int x = w * 16 + n;
    f32x4 acc[2] = {};
    #pragma unroll
    for (int row = 0; row < 3; row++) {
        #pragma unroll
        for (int dx = 0; dx < 3; dx++) {
            int tap = row * 3 + dx;
            #pragma unroll
            for (int kc = 0; kc < 2; kc++) {
                bf16x8 bv = *(const bf16x8*)(
                    sfr + ((((kc * 4 + q) * 3) + row) * 66 + x + dx) * 8);
                #pragma unroll
                for (int mt = 0; mt < 2; mt++) {
                    bf16x8 av = *(const bf16x8*)(
                        w3 + ((tap * 2 + mt) * 16 + n) * EMB + kc * 32 + q * 8);
                    acc[mt] = mfma16(av, bv, acc[mt]);
                }
            }
        }
    }
    #pragma unroll
    for (int mt = 0; mt < 2; mt++) {
        #pragma unroll
        for (int r = 0; r < 4; r++) {
            int m = mt * 16 + q * 4 + r;
            if (m < 25)
                dst[((size_t)(b * 25 + m)) * plane + y * width + x0 + x] =
                    acc[mt][r] + b_ce[m];
        }
    }
}

// ---------------------------------------------------------------------------
// K4 (fused softmax + CARAFE + blend), v3:
//   - LDS de tile re-laid channel-innermost sde[row][col][18] (+2 pad for
//     8B-aligned float2 reads; lane aliasing is 2-way = free; upper wave
//     half reads identical addrs = broadcast). 400 ds_read_b32 -> 200 b64.
//   - All 16 en float2 loads hoisted to ev[] at kernel top: HBM latency
//     hides under de-staging + softmax instead of being exposed per 2 ch.
//   - c-loop fully unrolled (ev is a register array - rule #20).
// ---------------------------------------------------------------------------
#define NCH 16
__global__ __launch_bounds__(256) void k_final(
        const float* __restrict__ en, const float* __restrict__ de,
        const float* __restrict__ tmp1, const float* __restrict__ tmp2,
        const float* __restrict__ gate_lr, float* __restrict__ out) {
    __shared__ float sde[8][36][NCH + 2];         // 20736 B
    int t = threadIdx.x;
    int x0 = (blockIdx.x & 1) * 32, y0 = (blockIdx.x >> 1) * 4;
    int c0 = blockIdx.y * NCH;
    int b = blockIdx.z;

    int tx = t & 31;
    int tyr = t >> 5;                 // 0..7 ; wave = {tx 0..31} x {r 0,1}
    int ty = tyr >> 1, r = tyr & 1;
    int yl = y0 + ty, xl = x0 + tx;
    int hrow = 2 * yl + r;
    int p0 = hrow * WO + 2 * xl;      // hi px 0; hi px 1 = p0+1
    int pl = yl * W + xl;             // lo px

    // issue all en loads + gate first: latency hides under staging+softmax
    const float* ebase = en + ((size_t)b * C + c0) * HWO + p0;
    float* obase = out + ((size_t)b * C + c0) * HWO + p0;
    float2 ev[NCH];
    #pragma unroll
    for (int c = 0; c < NCH; c++)
        ev[c] = *(const float2*)(ebase + (size_t)c * HWO);
    float g = gate_lr[b * HW + pl];

    const float* dbase = de + ((size_t)b * C + c0) * HW;
    for (int idx = t; idx < NCH * 288; idx += 256) {
        int c = idx / 288, rem = idx % 288;
        int row = rem / 36, col = rem % 36;
        int yy = y0 - 2 + row, xx = x0 - 2 + col;
        float v = 0.f;
        if ((unsigned)yy < (unsigned)H && (unsigned)xx < (unsigned)W)
            v = dbase[(size_t)c * HW + yy * W + xx];
        sde[row][col][c] = v;
    }

    // logits for the 2 hi px of this thread; softmax in-register
    float l0[25], l1[25];
    const float* t1 = tmp1 + (((size_t)b * 25) << 14) + p0;
    const float* t2 = tmp2 + (((size_t)b * 25) << 12) + pl;
    float mx0 = -1e30f, mx1 = -1e30f;
    #pragma unroll
    for (int q = 0; q < 25; q++) {
        float2 a = *(const float2*)(t1 + ((size_t)q << 14));
        float cq = t2[(size_t)q << 12];
        l0[q] = a.x + cq; l1[q] = a.y + cq;
        mx0 = fmaxf(mx0, l0[q]); mx1 = fmaxf(mx1, l1[q]);
    }
    float s0 = 0.f, s1 = 0.f;
    #pragma unroll
    for (int q = 0; q < 25; q++) {
        l0[q] = __expf(l0[q] - mx0); s0 += l0[q];
        l1[q] = __expf(l1[q] - mx1); s1 += l1[q];
    }
    float gi0 = (1.f - g) / s0;       // fold softmax 1/sum into blend weight
    float gi1 = (1.f - g) / s1;
    __syncthreads();

    #pragma unroll
    for (int cp = 0; cp < NCH / 2; cp++) {
        float a00 = 0.f, a01 = 0.f, a10 = 0.f, a11 = 0.f;
        #pragma unroll
        for (int dy = 0; dy < 5; dy++) {
            #pragma unroll
            for (int dx = 0; dx < 5; dx++) {
                float2 v = *(const float2*)&sde[ty + dy][tx + dx][2 * cp];
                int k = dy * 5 + dx;
                a00 += l0[k] * v.x;  a10 += l1[k] * v.x;
                a01 += l0[k] * v.y;  a11 += l1[k] * v.y;
            }
        }
        float2 e0 = ev[2 * cp], e1 = ev[2 * cp + 1];
        float2 o0, o1;
        o0.x = g * e0.x + gi0 * a00;  o0.y = g * e0.y + gi1 * a10;
        o1.x = g * e1.x + gi0 * a01;  o1.y = g * e1.y + gi1 * a11;
        *(float2*)(obase + (size_t)(2 * cp) * HWO) = o0;
        *(float2*)(obase + (size_t)(2 * cp + 1) * HWO) = o1;
    }
}

extern "C" void kernel_launch(void* const* d_in, const int* in_sizes, int n_in,
                              void* d_out, int out_size, void* d_ws, size_t ws_size,
                              hipStream_t stream) {
    const float* en     = (const float*)d_in[0];
    const float* de     = (const float*)d_in[1];
    const float* w_gate = (const float*)d_in[2];
    const float* b_gate = (const float*)d_in[3];
    const float* w_cen  = (const float*)d_in[4];
    const float* b_cen  = (const float*)d_in[5];
    const float* w_cde  = (const float*)d_in[6];
    const float* w_ce   = (const float*)d_in[7];
    const float* b_ce   = (const float*)d_in[8];
    float* out = (float*)d_out;

    __bf16* wsb     = (__bf16*)d_ws;
    __bf16* wbf_cen = wsb;                   // 16384
    __bf16* wdec5   = wbf_cen + 16384;       // 20480
    __bf16* w3      = wdec5 + 20480;         // 18432
    __bf16* enc_t   = w3 + 18432;            // 4194304
    __bf16* dec_t   = enc_t + 4194304;       // 1048576
    float* wsf     = (float*)((char*)d_ws + (size_t)(16384 + 20480 + 18432
                              + 4194304 + 1048576) * 2);
    float* tmp1    = wsf;                    // 1638400
    float* tmp2    = tmp1 + 1638400;         // 409600
    float* gate_lr = tmp2 + 409600;          // 16384

    k_prep2<<<80, 256, 0, stream>>>(w_cen, w_cde, w_gate, w_ce,
                                    wbf_cen, wdec5, w3);
    k_gemm1<<<640, 256, 0, stream>>>(en, de, wbf_cen, wdec5, b_cen, b_gate,
                                     enc_t, dec_t, gate_lr);
    k_conv3m<<<1280, 256, 0, stream>>>(enc_t, dec_t, w3, b_ce, tmp1, tmp2);
    k_final<<<dim3(32, 16, 4), 256, 0, stream>>>(en, de, tmp1, tmp2,
                                                 gate_lr, out);
}

// Round 5
// 223.453 us; speedup vs baseline: 1.1181x; 1.1181x over previous
//
#include <hip/hip_runtime.h>
#include <math.h>

#define BB 4
#define C 256
#define H 64
#define W 64
#define HW 4096
#define HO 128
#define WO 128
#define HWO 16384
#define EMB 64

typedef __bf16 bf16x8 __attribute__((ext_vector_type(8)));
typedef __bf16 bf16x4 __attribute__((ext_vector_type(4)));
typedef float  f32x4  __attribute__((ext_vector_type(4)));

__device__ __forceinline__ f32x4 mfma16(bf16x8 a, bf16x8 b, f32x4 c) {
    return __builtin_amdgcn_mfma_f32_16x16x32_bf16(a, b, c, 0, 0, 0);
}

// ---------------------------------------------------------------------------
// K1: weight tables (bf16)
//   wbf_cen: [e][c] (=w_cen layout, cast)
//   wdec5:   [5mt][16m][256c]; mt<4 = w_cde; mt=4 row0 = w_gate, rest 0
//   w3:      [tap9][mt2][16m][64e], rows m>=25 zeroed
// ---------------------------------------------------------------------------
__global__ void k_prep2(const float* __restrict__ w_cen,
                        const float* __restrict__ w_cde,
                        const float* __restrict__ w_gate,
                        const float* __restrict__ w_ce,
                        __bf16* __restrict__ wbf_cen,
                        __bf16* __restrict__ wdec5,
                        __bf16* __restrict__ w3) {
    for (int idx = blockIdx.x * blockDim.x + threadIdx.x; idx < 16384;
         idx += gridDim.x * blockDim.x)
        wbf_cen[idx] = (__bf16)w_cen[idx];
    for (int idx = blockIdx.x * blockDim.x + threadIdx.x; idx < 20480;
         idx += gridDim.x * blockDim.x) {
        int c = idx & 255, m = (idx >> 8) & 15;
        float v;
        if (idx < 16384) v = w_cde[idx];
        else             v = (m == 0) ? w_gate[c] : 0.f;
        wdec5[idx] = (__bf16)v;
    }
    for (int idx = blockIdx.x * blockDim.x + threadIdx.x; idx < 18432;
         idx += gridDim.x * blockDim.x) {
        int e = idx & 63;
        int m = (idx >> 6) & 15;
        int mt = (idx >> 10) & 1;
        int tap = idx >> 11;
        int q = mt * 16 + m;
        int dy = tap / 3, dx = tap % 3;
        w3[idx] = (q < 25) ? (__bf16)w_ce[((q * EMB + e) * 3 + dy) * 3 + dx]
                           : (__bf16)0.0f;
    }
}

// ---------------------------------------------------------------------------
// K2: MFMA GEMM Y[px][e] = Wt[e][c]·X[c][px], double-buffered LDS, 128-px
//   tiles. blocks [0,512): enc (+b_cen); [512,640): dec (+gate row)
// ---------------------------------------------------------------------------
__global__ __launch_bounds__(256) void k_gemm1(
        const float* __restrict__ en, const float* __restrict__ de,
        const __bf16* __restrict__ wbf_cen, const __bf16* __restrict__ wdec5,
        const float* __restrict__ b_cen, const float* __restrict__ b_gate,
        __bf16* __restrict__ enc_t, __bf16* __restrict__ dec_t,
        float* __restrict__ gate_lr) {
    __shared__ float xs[2][32][136];              // 34816 B
    int t = threadIdx.x;
    int w = t >> 6, lane = t & 63;
    int n = lane & 15, q = lane >> 4;
    bool isenc = blockIdx.x < 512;
    const float* X; const __bf16* Wt; __bf16* Y; int plane, px0, b;
    if (isenc) {
        int blk = blockIdx.x; b = blk >> 7; px0 = (blk & 127) << 7;
        X = en + (size_t)b * C * HWO; plane = HWO; Wt = wbf_cen;
        Y = enc_t + (size_t)b * HWO * EMB;
    } else {
        int blk = blockIdx.x - 512; b = blk >> 5; px0 = (blk & 31) << 7;
        X = de + (size_t)b * C * HW; plane = HW; Wt = wdec5;
        Y = dec_t + (size_t)b * HW * EMB;
    }
    int scc = t >> 5;                 // staging c row 0..7
    int sp4 = (t & 31) << 2;          // staging px offset
    float4 pre[4];
    #pragma unroll
    for (int i = 0; i < 4; i++)
        pre[i] = *(const float4*)(X + (size_t)(i * 8 + scc) * plane + px0 + sp4);
    #pragma unroll
    for (int i = 0; i < 4; i++)
        *(float4*)(&xs[0][i * 8 + scc][sp4]) = pre[i];
    __syncthreads();

    f32x4 acc[4][2] = {};
    f32x4 accg[2] = {};
    for (int kc = 0; kc < 8; kc++) {
        int cur = kc & 1;
        if (kc < 7) {
            int c1 = (kc + 1) * 32;
            #pragma unroll
            for (int i = 0; i < 4; i++)
                pre[i] = *(const float4*)(X + (size_t)(c1 + i * 8 + scc) * plane
                                          + px0 + sp4);
        }
        int c0 = kc * 32;
        bf16x8 af[4];
        #pragma unroll
        for (int mt = 0; mt < 4; mt++)
            af[mt] = *(const bf16x8*)(Wt + (size_t)(mt * 16 + n) * C + c0 + q * 8);
        bf16x8 bv[2];
        #pragma unroll
        for (int nt = 0; nt < 2; nt++) {
            int px = w * 32 + nt * 16 + n;
            #pragma unroll
            for (int j = 0; j < 8; j++)
                bv[nt][j] = (__bf16)xs[cur][q * 8 + j][px];
        }
        #pragma unroll
        for (int mt = 0; mt < 4; mt++) {
            acc[mt][0] = mfma16(af[mt], bv[0], acc[mt][0]);
            acc[mt][1] = mfma16(af[mt], bv[1], acc[mt][1]);
        }
        if (!isenc) {
            bf16x8 ag = *(const bf16x8*)(Wt + (size_t)(64 + n) * C + c0 + q * 8);
            accg[0] = mfma16(ag, bv[0], accg[0]);
            accg[1] = mfma16(ag, bv[1], accg[1]);
        }
        if (kc < 7) {
            #pragma unroll
            for (int i = 0; i < 4; i++)
                *(float4*)(&xs[cur ^ 1][i * 8 + scc][sp4]) = pre[i];
        }
        __syncthreads();
    }

    #pragma unroll
    for (int nt = 0; nt < 2; nt++) {
        int gpx = px0 + w * 32 + nt * 16 + n;
        #pragma unroll
        for (int mt = 0; mt < 4; mt++) {
            int e0 = mt * 16 + q * 4;
            bf16x4 ov;
            #pragma unroll
            for (int r = 0; r < 4; r++) {
                float bias = isenc ? b_cen[e0 + r] : 0.f;
                ov[r] = (__bf16)(acc[mt][nt][r] + bias);
            }
            *(bf16x4*)(Y + (size_t)gpx * EMB + e0) = ov;
        }
        if (!isenc && q == 0)
            gate_lr[b * HW + gpx] =
                1.f / (1.f + __expf(-(accg[nt][0] + b_gate[0])));
    }
}

// ---------------------------------------------------------------------------
// K3: 3x3 conv 64->25 via MFMA; 3 input rows staged in LDS in fragment order
//     (zero-padded halo). blocks [0,1024): enc_t->tmp1; [1024,1280): dec_t->tmp2
// ---------------------------------------------------------------------------
__global__ __launch_bounds__(256) void k_conv3m(
        const __bf16* __restrict__ enc_t, const __bf16* __restrict__ dec_t,
        const __bf16* __restrict__ w3, const float* __restrict__ b_ce,
        float* __restrict__ tmp1, float* __restrict__ tmp2) {
    __shared__ __bf16 sfr[8 * 3 * 66 * 8];        // 25.3 KB
    int t = threadIdx.x;
    int w = t >> 6, lane = t & 63;
    int n = lane & 15, q = lane >> 4;
    bool hi = blockIdx.x < 1024;
    const __bf16* src; float* dst; int b, y, width, plane, x0;
    if (hi) {
        int blk = blockIdx.x; b = blk >> 8; int r = blk & 255;
        y = r >> 1; x0 = (r & 1) * 64;
        width = WO; plane = HWO;
        src = enc_t + (size_t)b * HWO * EMB; dst = tmp1;
    } else {
        int blk = blockIdx.x - 1024; b = blk >> 6; y = blk & 63; x0 = 0;
        width = W; plane = HW;
        src = dec_t + (size_t)b * HW * EMB; dst = tmp2;
    }
    bf16x8 zf;
    #pragma unroll
    for (int j = 0; j < 8; j++) zf[j] = (__bf16)0.0f;
    for (int idx = t; idx < 1584; idx += 256) {
        int f = idx & 7;
        int rem = idx >> 3;
        int xloc = rem % 66, row = rem / 66;
        int yy = y + row - 1, xg = x0 - 1 + xloc;
        bf16x8 v = zf;
        if ((unsigned)yy < (unsigned)width && (unsigned)xg < (unsigned)width)
            v = *(const bf16x8*)(src + ((size_t)yy * width + xg) * EMB + f * 8);
        *(bf16x8*)(sfr + (((f * 3) + row) * 66 + xloc) * 8) = v;
    }
    __syncthreads();

    int x = w * 16 + n;
    f32x4 acc[2] = {};
    #pragma unroll
    for (int row = 0; row < 3; row++) {
        #pragma unroll
        for (int dx = 0; dx < 3; dx++) {
            int tap = row * 3 + dx;
            #pragma unroll
            for (int kc = 0; kc < 2; kc++) {
                bf16x8 bv = *(const bf16x8*)(
                    sfr + ((((kc * 4 + q) * 3) + row) * 66 + x + dx) * 8);
                #pragma unroll
                for (int mt = 0; mt < 2; mt++) {
                    bf16x8 av = *(const bf16x8*)(
                        w3 + ((tap * 2 + mt) * 16 + n) * EMB + kc * 32 + q * 8);
                    acc[mt] = mfma16(av, bv, acc[mt]);
                }
            }
        }
    }
    #pragma unroll
    for (int mt = 0; mt < 2; mt++) {
        #pragma unroll
        for (int r = 0; r < 4; r++) {
            int m = mt * 16 + q * 4 + r;
            if (m < 25)
                dst[((size_t)(b * 25 + m)) * plane + y * width + x0 + x] =
                    acc[mt][r] + b_ce[m];
        }
    }
}

// ---------------------------------------------------------------------------
// K4 (fused softmax + CARAFE + blend), v4:
//   - sde channel-innermost [row][col][18] (R4): 400 ds_read_b32 ->
//     200 ds_read_b64; bank conflicts measured negligible (294K cyc/kernel).
//   - en loads back IN the channel loop, unroll 2 (R3): the R4 ev[16] hoist
//     cost +32 VGPR (64->96), dropped occupancy 8->5 waves/SIMD and scaled
//     dur by exactly 1.6x. TLP at 8 waves/SIMD already hides en latency.
// ---------------------------------------------------------------------------
#define NCH 16
__global__ __launch_bounds__(256) void k_final(
        const float* __restrict__ en, const float* __restrict__ de,
        const float* __restrict__ tmp1, const float* __restrict__ tmp2,
        const float* __restrict__ gate_lr, float* __restrict__ out) {
    __shared__ float sde[8][36][NCH + 2];         // 20736 B
    int t = threadIdx.x;
    int x0 = (blockIdx.x & 1) * 32, y0 = (blockIdx.x >> 1) * 4;
    int c0 = blockIdx.y * NCH;
    int b = blockIdx.z;

    const float* dbase = de + ((size_t)b * C + c0) * HW;
    for (int idx = t; idx < NCH * 288; idx += 256) {
        int c = idx / 288, rem = idx % 288;
        int row = rem / 36, col = rem % 36;
        int yy = y0 - 2 + row, xx = x0 - 2 + col;
        float v = 0.f;
        if ((unsigned)yy < (unsigned)H && (unsigned)xx < (unsigned)W)
            v = dbase[(size_t)c * HW + yy * W + xx];
        sde[row][col][c] = v;
    }

    int tx = t & 31;
    int tyr = t >> 5;                 // 0..7 ; wave = {tx 0..31} x {r 0,1}
    int ty = tyr >> 1, r = tyr & 1;
    int yl = y0 + ty, xl = x0 + tx;
    int hrow = 2 * yl + r;
    int p0 = hrow * WO + 2 * xl;      // hi px 0; hi px 1 = p0+1
    int pl = yl * W + xl;             // lo px

    // logits for the 2 hi px of this thread; softmax in-register
    float l0[25], l1[25];
    const float* t1 = tmp1 + (((size_t)b * 25) << 14) + p0;
    const float* t2 = tmp2 + (((size_t)b * 25) << 12) + pl;
    float mx0 = -1e30f, mx1 = -1e30f;
    #pragma unroll
    for (int q = 0; q < 25; q++) {
        float2 a = *(const float2*)(t1 + ((size_t)q << 14));
        float cq = t2[(size_t)q << 12];
        l0[q] = a.x + cq; l1[q] = a.y + cq;
        mx0 = fmaxf(mx0, l0[q]); mx1 = fmaxf(mx1, l1[q]);
    }
    float s0 = 0.f, s1 = 0.f;
    #pragma unroll
    for (int q = 0; q < 25; q++) {
        l0[q] = __expf(l0[q] - mx0); s0 += l0[q];
        l1[q] = __expf(l1[q] - mx1); s1 += l1[q];
    }
    float g = gate_lr[b * HW + pl];
    float gi0 = (1.f - g) / s0;       // fold softmax 1/sum into blend weight
    float gi1 = (1.f - g) / s1;
    __syncthreads();

    const float* ebase = en + ((size_t)b * C + c0) * HWO + p0;
    float* obase = out + ((size_t)b * C + c0) * HWO + p0;
    #pragma unroll 2
    for (int cp = 0; cp < NCH / 2; cp++) {
        float a00 = 0.f, a01 = 0.f, a10 = 0.f, a11 = 0.f;
        #pragma unroll
        for (int dy = 0; dy < 5; dy++) {
            #pragma unroll
            for (int dx = 0; dx < 5; dx++) {
                float2 v = *(const float2*)&sde[ty + dy][tx + dx][2 * cp];
                int k = dy * 5 + dx;
                a00 += l0[k] * v.x;  a10 += l1[k] * v.x;
                a01 += l0[k] * v.y;  a11 += l1[k] * v.y;
            }
        }
        float2 e0 = *(const float2*)(ebase + (size_t)(2 * cp) * HWO);
        float2 e1 = *(const float2*)(ebase + (size_t)(2 * cp + 1) * HWO);
        float2 o0, o1;
        o0.x = g * e0.x + gi0 * a00;  o0.y = g * e0.y + gi1 * a10;
        o1.x = g * e1.x + gi0 * a01;  o1.y = g * e1.y + gi1 * a11;
        *(float2*)(obase + (size_t)(2 * cp) * HWO) = o0;
        *(float2*)(obase + (size_t)(2 * cp + 1) * HWO) = o1;
    }
}

extern "C" void kernel_launch(void* const* d_in, const int* in_sizes, int n_in,
                              void* d_out, int out_size, void* d_ws, size_t ws_size,
                              hipStream_t stream) {
    const float* en     = (const float*)d_in[0];
    const float* de     = (const float*)d_in[1];
    const float* w_gate = (const float*)d_in[2];
    const float* b_gate = (const float*)d_in[3];
    const float* w_cen  = (const float*)d_in[4];
    const float* b_cen  = (const float*)d_in[5];
    const float* w_cde  = (const float*)d_in[6];
    const float* w_ce   = (const float*)d_in[7];
    const float* b_ce   = (const float*)d_in[8];
    float* out = (float*)d_out;

    __bf16* wsb     = (__bf16*)d_ws;
    __bf16* wbf_cen = wsb;                   // 16384
    __bf16* wdec5   = wbf_cen + 16384;       // 20480
    __bf16* w3      = wdec5 + 20480;         // 18432
    __bf16* enc_t   = w3 + 18432;            // 4194304
    __bf16* dec_t   = enc_t + 4194304;       // 1048576
    float* wsf     = (float*)((char*)d_ws + (size_t)(16384 + 20480 + 18432
                              + 4194304 + 1048576) * 2);
    float* tmp1    = wsf;                    // 1638400
    float* tmp2    = tmp1 + 1638400;         // 409600
    float* gate_lr = tmp2 + 409600;          // 16384

    k_prep2<<<80, 256, 0, stream>>>(w_cen, w_cde, w_gate, w_ce,
                                    wbf_cen, wdec5, w3);
    k_gemm1<<<640, 256, 0, stream>>>(en, de, wbf_cen, wdec5, b_cen, b_gate,
                                     enc_t, dec_t, gate_lr);
    k_conv3m<<<1280, 256, 0, stream>>>(enc_t, dec_t, w3, b_ce, tmp1, tmp2);
    k_final<<<dim3(32, 16, 4), 256, 0, stream>>>(en, de, tmp1, tmp2,
                                                 gate_lr, out);
}

// Round 6
// 222.940 us; speedup vs baseline: 1.1207x; 1.0023x over previous
//
#include <hip/hip_runtime.h>
#include <math.h>

#define BB 4
#define C 256
#define H 64
#define W 64
#define HW 4096
#define HO 128
#define WO 128
#define HWO 16384
#define EMB 64

typedef __bf16 bf16x8 __attribute__((ext_vector_type(8)));
typedef __bf16 bf16x4 __attribute__((ext_vector_type(4)));
typedef float  f32x4  __attribute__((ext_vector_type(4)));

__device__ __forceinline__ f32x4 mfma16(bf16x8 a, bf16x8 b, f32x4 c) {
    return __builtin_amdgcn_mfma_f32_16x16x32_bf16(a, b, c, 0, 0, 0);
}

// ---------------------------------------------------------------------------
// K1: weight tables (bf16)
//   wbf_cen: [e][c] (=w_cen layout, cast)
//   wdec5:   [5mt][16m][256c]; mt<4 = w_cde; mt=4 row0 = w_gate, rest 0
//   w3:      [tap9][mt2][16m][64e], rows m>=25 zeroed
// ---------------------------------------------------------------------------
__global__ void k_prep2(const float* __restrict__ w_cen,
                        const float* __restrict__ w_cde,
                        const float* __restrict__ w_gate,
                        const float* __restrict__ w_ce,
                        __bf16* __restrict__ wbf_cen,
                        __bf16* __restrict__ wdec5,
                        __bf16* __restrict__ w3) {
    for (int idx = blockIdx.x * blockDim.x + threadIdx.x; idx < 16384;
         idx += gridDim.x * blockDim.x)
        wbf_cen[idx] = (__bf16)w_cen[idx];
    for (int idx = blockIdx.x * blockDim.x + threadIdx.x; idx < 20480;
         idx += gridDim.x * blockDim.x) {
        int c = idx & 255, m = (idx >> 8) & 15;
        float v;
        if (idx < 16384) v = w_cde[idx];
        else             v = (m == 0) ? w_gate[c] : 0.f;
        wdec5[idx] = (__bf16)v;
    }
    for (int idx = blockIdx.x * blockDim.x + threadIdx.x; idx < 18432;
         idx += gridDim.x * blockDim.x) {
        int e = idx & 63;
        int m = (idx >> 6) & 15;
        int mt = (idx >> 10) & 1;
        int tap = idx >> 11;
        int q = mt * 16 + m;
        int dy = tap / 3, dx = tap % 3;
        w3[idx] = (q < 25) ? (__bf16)w_ce[((q * EMB + e) * 3 + dy) * 3 + dx]
                           : (__bf16)0.0f;
    }
}

// ---------------------------------------------------------------------------
// K2 (v2, LDS-free): Y[px][e] = Wt[e][c]·X[c][px].
//   X has ZERO intra-kernel reuse (each X[c][px] feeds exactly one lane's
//   fragment) -> LDS staging was pure overhead: ds_writes + 4-way-conflicted
//   column ds_reads (row stride 136: 8-row q-groups alias the same bank) +
//   8 barrier/vmcnt drains per block. Now each lane loads its 8 fragment
//   elems straight from global (4 q-rows x 64B contiguous per instr),
//   1-deep register prefetch, no barriers. 64-px tiles: blocks [0,1024):
//   enc (+b_cen); [1024,1280): dec (+gate row).
// ---------------------------------------------------------------------------
__global__ __launch_bounds__(256) void k_gemm1(
        const float* __restrict__ en, const float* __restrict__ de,
        const __bf16* __restrict__ wbf_cen, const __bf16* __restrict__ wdec5,
        const float* __restrict__ b_cen, const float* __restrict__ b_gate,
        __bf16* __restrict__ enc_t, __bf16* __restrict__ dec_t,
        float* __restrict__ gate_lr) {
    int t = threadIdx.x;
    int w = t >> 6, lane = t & 63;
    int n = lane & 15, q = lane >> 4;
    bool isenc = blockIdx.x < 1024;
    const float* X; const __bf16* Wt; __bf16* Y; int plane, px0, b;
    if (isenc) {
        int blk = blockIdx.x; b = blk >> 8; px0 = (blk & 255) << 6;
        X = en + (size_t)b * C * HWO; plane = HWO; Wt = wbf_cen;
        Y = enc_t + (size_t)b * HWO * EMB;
    } else {
        int blk = blockIdx.x - 1024; b = blk >> 6; px0 = (blk & 63) << 6;
        X = de + (size_t)b * C * HW; plane = HW; Wt = wdec5;
        Y = dec_t + (size_t)b * HW * EMB;
    }
    int px = px0 + w * 16 + n;
    const float* Xp = X + (size_t)(q * 8) * plane + px;

    f32x4 acc[4] = {};
    f32x4 accg = {};
    float cur[8];
    #pragma unroll
    for (int j = 0; j < 8; j++) cur[j] = Xp[(size_t)j * plane];

    for (int kc = 0; kc < 8; kc++) {
        float nxt[8];
        if (kc < 7) {
            const float* Xn = Xp + (size_t)((kc + 1) * 32) * plane;
            #pragma unroll
            for (int j = 0; j < 8; j++) nxt[j] = Xn[(size_t)j * plane];
        }
        bf16x8 bv;
        #pragma unroll
        for (int j = 0; j < 8; j++) bv[j] = (__bf16)cur[j];
        int c0 = kc * 32;
        #pragma unroll
        for (int mt = 0; mt < 4; mt++) {
            bf16x8 af = *(const bf16x8*)(Wt + (size_t)(mt * 16 + n) * C
                                         + c0 + q * 8);
            acc[mt] = mfma16(af, bv, acc[mt]);
        }
        if (!isenc) {
            bf16x8 ag = *(const bf16x8*)(Wt + (size_t)(64 + n) * C + c0 + q * 8);
            accg = mfma16(ag, bv, accg);
        }
        if (kc < 7) {
            #pragma unroll
            for (int j = 0; j < 8; j++) cur[j] = nxt[j];
        }
    }

    #pragma unroll
    for (int mt = 0; mt < 4; mt++) {
        int e0 = mt * 16 + q * 4;
        bf16x4 ov;
        #pragma unroll
        for (int r = 0; r < 4; r++) {
            float bias = isenc ? b_cen[e0 + r] : 0.f;
            ov[r] = (__bf16)(acc[mt][r] + bias);
        }
        *(bf16x4*)(Y + (size_t)px * EMB + e0) = ov;
    }
    if (!isenc && q == 0)
        gate_lr[b * HW + px] = 1.f / (1.f + __expf(-(accg[0] + b_gate[0])));
}

// ---------------------------------------------------------------------------
// K3: 3x3 conv 64->25 via MFMA; 3 input rows staged in LDS in fragment order
//     (zero-padded halo). blocks [0,1024): enc_t->tmp1; [1024,1280): dec_t->tmp2
// ---------------------------------------------------------------------------
__global__ __launch_bounds__(256) void k_conv3m(
        const __bf16* __restrict__ enc_t, const __bf16* __restrict__ dec_t,
        const __bf16* __restrict__ w3, const float* __restrict__ b_ce,
        float* __restrict__ tmp1, float* __restrict__ tmp2) {
    __shared__ __bf16 sfr[8 * 3 * 66 * 8];        // 25.3 KB
    int t = threadIdx.x;
    int w = t >> 6, lane = t & 63;
    int n = lane & 15, q = lane >> 4;
    bool hi = blockIdx.x < 1024;
    const __bf16* src; float* dst; int b, y, width, plane, x0;
    if (hi) {
        int blk = blockIdx.x; b = blk >> 8; int r = blk & 255;
        y = r >> 1; x0 = (r & 1) * 64;
        width = WO; plane = HWO;
        src = enc_t + (size_t)b * HWO * EMB; dst = tmp1;
    } else {
        int blk = blockIdx.x - 1024; b = blk >> 6; y = blk & 63; x0 = 0;
        width = W; plane = HW;
        src = dec_t + (size_t)b * HW * EMB; dst = tmp2;
    }
    bf16x8 zf;
    #pragma unroll
    for (int j = 0; j < 8; j++) zf[j] = (__bf16)0.0f;
    for (int idx = t; idx < 1584; idx += 256) {
        int f = idx & 7;
        int rem = idx >> 3;
        int xloc = rem % 66, row = rem / 66;
        int yy = y + row - 1, xg = x0 - 1 + xloc;
        bf16x8 v = zf;
        if ((unsigned)yy < (unsigned)width && (unsigned)xg < (unsigned)width)
            v = *(const bf16x8*)(src + ((size_t)yy * width + xg) * EMB + f * 8);
        *(bf16x8*)(sfr + (((f * 3) + row) * 66 + xloc) * 8) = v;
    }
    __syncthreads();

    int x = w * 16 + n;
    f32x4 acc[2] = {};
    #pragma unroll
    for (int row = 0; row < 3; row++) {
        #pragma unroll
        for (int dx = 0; dx < 3; dx++) {
            int tap = row * 3 + dx;
            #pragma unroll
            for (int kc = 0; kc < 2; kc++) {
                bf16x8 bv = *(const bf16x8*)(
                    sfr + ((((kc * 4 + q) * 3) + row) * 66 + x + dx) * 8);
                #pragma unroll
                for (int mt = 0; mt < 2; mt++) {
                    bf16x8 av = *(const bf16x8*)(
                        w3 + ((tap * 2 + mt) * 16 + n) * EMB + kc * 32 + q * 8);
                    acc[mt] = mfma16(av, bv, acc[mt]);
                }
            }
        }
    }
    #pragma unroll
    for (int mt = 0; mt < 2; mt++) {
        #pragma unroll
        for (int r = 0; r < 4; r++) {
            int m = mt * 16 + q * 4 + r;
            if (m < 25)
                dst[((size_t)(b * 25 + m)) * plane + y * width + x0 + x] =
                    acc[mt][r] + b_ce[m];
        }
    }
}

// ---------------------------------------------------------------------------
// K4 (fused softmax + CARAFE + blend) — R3-proven version (52.8 us, VGPR 64,
//   8 waves/SIMD). sde c-major scalar reads; en loads in-loop (unroll 2).
//   Lessons: ev[16] hoist (+32 VGPR) and sde float2 relayout (+4 VGPR,
//   crosses the 64-reg occupancy boundary) both regressed.
// ---------------------------------------------------------------------------
#define NCH 16
__global__ __launch_bounds__(256) void k_final(
        const float* __restrict__ en, const float* __restrict__ de,
        const float* __restrict__ tmp1, const float* __restrict__ tmp2,
        const float* __restrict__ gate_lr, float* __restrict__ out) {
    __shared__ float sde[NCH][8][36];             // 18432 B
    int t = threadIdx.x;
    int x0 = (blockIdx.x & 1) * 32, y0 = (blockIdx.x >> 1) * 4;
    int c0 = blockIdx.y * NCH;
    int b = blockIdx.z;

    const float* dbase = de + ((size_t)b * C + c0) * HW;
    for (int idx = t; idx < NCH * 288; idx += 256) {
        int c = idx / 288, rem = idx % 288;
        int row = rem / 36, col = rem % 36;
        int yy = y0 - 2 + row, xx = x0 - 2 + col;
        float v = 0.f;
        if ((unsigned)yy < (unsigned)H && (unsigned)xx < (unsigned)W)
            v = dbase[(size_t)c * HW + yy * W + xx];
        sde[c][row][col] = v;
    }

    int tx = t & 31;
    int tyr = t >> 5;                 // 0..7 ; wave = {tx 0..31} x {r 0,1}
    int ty = tyr >> 1, r = tyr & 1;
    int yl = y0 + ty, xl = x0 + tx;
    int hrow = 2 * yl + r;
    int p0 = hrow * WO + 2 * xl;      // hi px 0; hi px 1 = p0+1
    int pl = yl * W + xl;             // lo px

    // logits for the 2 hi px of this thread; softmax in-register
    float l0[25], l1[25];
    const float* t1 = tmp1 + (((size_t)b * 25) << 14) + p0;
    const float* t2 = tmp2 + (((size_t)b * 25) << 12) + pl;
    float mx0 = -1e30f, mx1 = -1e30f;
    #pragma unroll
    for (int q = 0; q < 25; q++) {
        float2 a = *(const float2*)(t1 + ((size_t)q << 14));
        float cq = t2[(size_t)q << 12];
        l0[q] = a.x + cq; l1[q] = a.y + cq;
        mx0 = fmaxf(mx0, l0[q]); mx1 = fmaxf(mx1, l1[q]);
    }
    float s0 = 0.f, s1 = 0.f;
    #pragma unroll
    for (int q = 0; q < 25; q++) {
        l0[q] = __expf(l0[q] - mx0); s0 += l0[q];
        l1[q] = __expf(l1[q] - mx1); s1 += l1[q];
    }
    float g = gate_lr[b * HW + pl];
    float gi0 = (1.f - g) / s0;       // fold softmax 1/sum into blend weight
    float gi1 = (1.f - g) / s1;
    __syncthreads();

    const float* ebase = en + ((size_t)b * C + c0) * HWO + p0;
    float* obase = out + ((size_t)b * C + c0) * HWO + p0;
    #pragma unroll 2
    for (int c = 0; c < NCH; c++) {
        float a0 = 0.f, a1 = 0.f;
        #pragma unroll
        for (int dy = 0; dy < 5; dy++) {
            #pragma unroll
            for (int dx = 0; dx < 5; dx++) {
                float v = sde[c][ty + dy][tx + dx];
                int k = dy * 5 + dx;
                a0 += l0[k] * v;
                a1 += l1[k] * v;
            }
        }
        size_t cc = (size_t)c * HWO;
        float2 e = *(const float2*)(ebase + cc);
        float2 o;
        o.x = g * e.x + gi0 * a0;
        o.y = g * e.y + gi1 * a1;
        *(float2*)(obase + cc) = o;
    }
}

extern "C" void kernel_launch(void* const* d_in, const int* in_sizes, int n_in,
                              void* d_out, int out_size, void* d_ws, size_t ws_size,
                              hipStream_t stream) {
    const float* en     = (const float*)d_in[0];
    const float* de     = (const float*)d_in[1];
    const float* w_gate = (const float*)d_in[2];
    const float* b_gate = (const float*)d_in[3];
    const float* w_cen  = (const float*)d_in[4];
    const float* b_cen  = (const float*)d_in[5];
    const float* w_cde  = (const float*)d_in[6];
    const float* w_ce   = (const float*)d_in[7];
    const float* b_ce   = (const float*)d_in[8];
    float* out = (float*)d_out;

    __bf16* wsb     = (__bf16*)d_ws;
    __bf16* wbf_cen = wsb;                   // 16384
    __bf16* wdec5   = wbf_cen + 16384;       // 20480
    __bf16* w3      = wdec5 + 20480;         // 18432
    __bf16* enc_t   = w3 + 18432;            // 4194304
    __bf16* dec_t   = enc_t + 4194304;       // 1048576
    float* wsf     = (float*)((char*)d_ws + (size_t)(16384 + 20480 + 18432
                              + 4194304 + 1048576) * 2);
    float* tmp1    = wsf;                    // 1638400
    float* tmp2    = tmp1 + 1638400;         // 409600
    float* gate_lr = tmp2 + 409600;          // 16384

    k_prep2<<<80, 256, 0, stream>>>(w_cen, w_cde, w_gate, w_ce,
                                    wbf_cen, wdec5, w3);
    k_gemm1<<<1280, 256, 0, stream>>>(en, de, wbf_cen, wdec5, b_cen, b_gate,
                                      enc_t, dec_t, gate_lr);
    k_conv3m<<<1280, 256, 0, stream>>>(enc_t, dec_t, w3, b_ce, tmp1, tmp2);
    k_final<<<dim3(32, 16, 4), 256, 0, stream>>>(en, de, tmp1, tmp2,
                                                 gate_lr, out);
}

// Round 7
// 214.108 us; speedup vs baseline: 1.1669x; 1.0412x over previous
//
#include <hip/hip_runtime.h>
#include <math.h>

#define BB 4
#define C 256
#define H 64
#define W 64
#define HW 4096
#define HO 128
#define WO 128
#define HWO 16384
#define EMB 64

typedef __bf16 bf16x8 __attribute__((ext_vector_type(8)));
typedef __bf16 bf16x4 __attribute__((ext_vector_type(4)));
typedef float  f32x4  __attribute__((ext_vector_type(4)));

__device__ __forceinline__ f32x4 mfma16(bf16x8 a, bf16x8 b, f32x4 c) {
    return __builtin_amdgcn_mfma_f32_16x16x32_bf16(a, b, c, 0, 0, 0);
}

// ---------------------------------------------------------------------------
// K1: weight tables (bf16)
//   wbf_cen: [e][c] (=w_cen layout, cast)
//   wdec5:   [5mt][16m][256c]; mt<4 = w_cde; mt=4 row0 = w_gate, rest 0
//   w3:      [tap9][mt2][16m][64e], rows m>=25 zeroed
// ---------------------------------------------------------------------------
__global__ void k_prep2(const float* __restrict__ w_cen,
                        const float* __restrict__ w_cde,
                        const float* __restrict__ w_gate,
                        const float* __restrict__ w_ce,
                        __bf16* __restrict__ wbf_cen,
                        __bf16* __restrict__ wdec5,
                        __bf16* __restrict__ w3) {
    for (int idx = blockIdx.x * blockDim.x + threadIdx.x; idx < 16384;
         idx += gridDim.x * blockDim.x)
        wbf_cen[idx] = (__bf16)w_cen[idx];
    for (int idx = blockIdx.x * blockDim.x + threadIdx.x; idx < 20480;
         idx += gridDim.x * blockDim.x) {
        int c = idx & 255, m = (idx >> 8) & 15;
        float v;
        if (idx < 16384) v = w_cde[idx];
        else             v = (m == 0) ? w_gate[c] : 0.f;
        wdec5[idx] = (__bf16)v;
    }
    for (int idx = blockIdx.x * blockDim.x + threadIdx.x; idx < 18432;
         idx += gridDim.x * blockDim.x) {
        int e = idx & 63;
        int m = (idx >> 6) & 15;
        int mt = (idx >> 10) & 1;
        int tap = idx >> 11;
        int q = mt * 16 + m;
        int dy = tap / 3, dx = tap % 3;
        w3[idx] = (q < 25) ? (__bf16)w_ce[((q * EMB + e) * 3 + dy) * 3 + dx]
                           : (__bf16)0.0f;
    }
}

// ---------------------------------------------------------------------------
// K2 (R3 LDS version + row-permuted tiles): Y[px][e] = Wt[e][c]·X[c][px],
//   double-buffered LDS, 128-px tiles.
//   Row permutation perm(r) = ((r&7)<<2)|(r>>3): fragment lane (n,q) reads
//   c-row q*8+j at LDS row (j<<2)|q -> bank = (8q+n)%32 -> 2 lanes/bank
//   (free, m136), vs 4-way conflict with the identity layout (8 rows x 136
//   floats == 0 mod 32 banks; unavoidable by padding since any 16B-aligned
//   stride keeps 8*stride == 0 mod 32).
//   R6 lesson: direct-global (no-LDS) gemm was +8 us — 64 scalar VMEM/thread
//   beats nothing; LDS staging also repairs load vectorization.
//   blocks [0,512): enc (+b_cen); [512,640): dec (+gate row)
// ---------------------------------------------------------------------------
__global__ __launch_bounds__(256) void k_gemm1(
        const float* __restrict__ en, const float* __restrict__ de,
        const __bf16* __restrict__ wbf_cen, const __bf16* __restrict__ wdec5,
        const float* __restrict__ b_cen, const float* __restrict__ b_gate,
        __bf16* __restrict__ enc_t, __bf16* __restrict__ dec_t,
        float* __restrict__ gate_lr) {
    __shared__ float xs[2][32][136];              // 34816 B
    int t = threadIdx.x;
    int w = t >> 6, lane = t & 63;
    int n = lane & 15, q = lane >> 4;
    bool isenc = blockIdx.x < 512;
    const float* X; const __bf16* Wt; __bf16* Y; int plane, px0, b;
    if (isenc) {
        int blk = blockIdx.x; b = blk >> 7; px0 = (blk & 127) << 7;
        X = en + (size_t)b * C * HWO; plane = HWO; Wt = wbf_cen;
        Y = enc_t + (size_t)b * HWO * EMB;
    } else {
        int blk = blockIdx.x - 512; b = blk >> 5; px0 = (blk & 31) << 7;
        X = de + (size_t)b * C * HW; plane = HW; Wt = wdec5;
        Y = dec_t + (size_t)b * HW * EMB;
    }
    int scc = t >> 5;                 // staging c row 0..7 (r = i*8+scc)
    int sp4 = (t & 31) << 2;          // staging px offset
    float4 pre[4];
    #pragma unroll
    for (int i = 0; i < 4; i++)
        pre[i] = *(const float4*)(X + (size_t)(i * 8 + scc) * plane + px0 + sp4);
    #pragma unroll
    for (int i = 0; i < 4; i++)
        *(float4*)(&xs[0][(scc << 2) | i][sp4]) = pre[i];   // perm(i*8+scc)
    __syncthreads();

    f32x4 acc[4][2] = {};
    f32x4 accg[2] = {};
    for (int kc = 0; kc < 8; kc++) {
        int cur = kc & 1;
        if (kc < 7) {
            int c1 = (kc + 1) * 32;
            #pragma unroll
            for (int i = 0; i < 4; i++)
                pre[i] = *(const float4*)(X + (size_t)(c1 + i * 8 + scc) * plane
                                          + px0 + sp4);
        }
        int c0 = kc * 32;
        bf16x8 af[4];
        #pragma unroll
        for (int mt = 0; mt < 4; mt++)
            af[mt] = *(const bf16x8*)(Wt + (size_t)(mt * 16 + n) * C + c0 + q * 8);
        bf16x8 bv[2];
        #pragma unroll
        for (int nt = 0; nt < 2; nt++) {
            int px = w * 32 + nt * 16 + n;
            #pragma unroll
            for (int j = 0; j < 8; j++)
                bv[nt][j] = (__bf16)xs[cur][(j << 2) | q][px];  // perm(q*8+j)
        }
        #pragma unroll
        for (int mt = 0; mt < 4; mt++) {
            acc[mt][0] = mfma16(af[mt], bv[0], acc[mt][0]);
            acc[mt][1] = mfma16(af[mt], bv[1], acc[mt][1]);
        }
        if (!isenc) {
            bf16x8 ag = *(const bf16x8*)(Wt + (size_t)(64 + n) * C + c0 + q * 8);
            accg[0] = mfma16(ag, bv[0], accg[0]);
            accg[1] = mfma16(ag, bv[1], accg[1]);
        }
        if (kc < 7) {
            #pragma unroll
            for (int i = 0; i < 4; i++)
                *(float4*)(&xs[cur ^ 1][(scc << 2) | i][sp4]) = pre[i];
        }
        __syncthreads();
    }

    #pragma unroll
    for (int nt = 0; nt < 2; nt++) {
        int gpx = px0 + w * 32 + nt * 16 + n;
        #pragma unroll
        for (int mt = 0; mt < 4; mt++) {
            int e0 = mt * 16 + q * 4;
            bf16x4 ov;
            #pragma unroll
            for (int r = 0; r < 4; r++) {
                float bias = isenc ? b_cen[e0 + r] : 0.f;
                ov[r] = (__bf16)(acc[mt][nt][r] + bias);
            }
            *(bf16x4*)(Y + (size_t)gpx * EMB + e0) = ov;
        }
        if (!isenc && q == 0)
            gate_lr[b * HW + gpx] =
                1.f / (1.f + __expf(-(accg[nt][0] + b_gate[0])));
    }
}

// ---------------------------------------------------------------------------
// K3: 3x3 conv 64->25 via MFMA; 3 input rows staged in LDS in fragment order
//     (zero-padded halo). blocks [0,1024): enc_t->tmp1; [1024,1280): dec_t->tmp2
// ---------------------------------------------------------------------------
__global__ __launch_bounds__(256) void k_conv3m(
        const __bf16* __restrict__ enc_t, const __bf16* __restrict__ dec_t,
        const __bf16* __restrict__ w3, const float* __restrict__ b_ce,
        float* __restrict__ tmp1, float* __restrict__ tmp2) {
    __shared__ __bf16 sfr[8 * 3 * 66 * 8];        // 25.3 KB
    int t = threadIdx.x;
    int w = t >> 6, lane = t & 63;
    int n = lane & 15, q = lane >> 4;
    bool hi = blockIdx.x < 1024;
    const __bf16* src; float* dst; int b, y, width, plane, x0;
    if (hi) {
        int blk = blockIdx.x; b = blk >> 8; int r = blk & 255;
        y = r >> 1; x0 = (r & 1) * 64;
        width = WO; plane = HWO;
        src = enc_t + (size_t)b * HWO * EMB; dst = tmp1;
    } else {
        int blk = blockIdx.x - 1024; b = blk >> 6; y = blk & 63; x0 = 0;
        width = W; plane = HW;
        src = dec_t + (size_t)b * HW * EMB; dst = tmp2;
    }
    bf16x8 zf;
    #pragma unroll
    for (int j = 0; j < 8; j++) zf[j] = (__bf16)0.0f;
    for (int idx = t; idx < 1584; idx += 256) {
        int f = idx & 7;
        int rem = idx >> 3;
        int xloc = rem % 66, row = rem / 66;
        int yy = y + row - 1, xg = x0 - 1 + xloc;
        bf16x8 v = zf;
        if ((unsigned)yy < (unsigned)width && (unsigned)xg < (unsigned)width)
            v = *(const bf16x8*)(src + ((size_t)yy * width + xg) * EMB + f * 8);
        *(bf16x8*)(sfr + (((f * 3) + row) * 66 + xloc) * 8) = v;
    }
    __syncthreads();

    int x = w * 16 + n;
    f32x4 acc[2] = {};
    #pragma unroll
    for (int row = 0; row < 3; row++) {
        #pragma unroll
        for (int dx = 0; dx < 3; dx++) {
            int tap = row * 3 + dx;
            #pragma unroll
            for (int kc = 0; kc < 2; kc++) {
                bf16x8 bv = *(const bf16x8*)(
                    sfr + ((((kc * 4 + q) * 3) + row) * 66 + x + dx) * 8);
                #pragma unroll
                for (int mt = 0; mt < 2; mt++) {
                    bf16x8 av = *(const bf16x8*)(
                        w3 + ((tap * 2 + mt) * 16 + n) * EMB + kc * 32 + q * 8);
                    acc[mt] = mfma16(av, bv, acc[mt]);
                }
            }
        }
    }
    #pragma unroll
    for (int mt = 0; mt < 2; mt++) {
        #pragma unroll
        for (int r = 0; r < 4; r++) {
            int m = mt * 16 + q * 4 + r;
            if (m < 25)
                dst[((size_t)(b * 25 + m)) * plane + y * width + x0 + x] =
                    acc[mt][r] + b_ce[m];
        }
    }
}

// ---------------------------------------------------------------------------
// K4 (fused softmax + CARAFE + blend) — R3-proven version (52.8 us, VGPR 64,
//   8 waves/SIMD). sde c-major scalar reads; en loads in-loop (unroll 2).
//   Lessons: ev[16] hoist (+32 VGPR) and sde float2 relayout (+4 VGPR,
//   crosses the 64-reg occupancy boundary) both regressed. Softmax
//   amortization via fewer blocks also rejected: wave-count loss outweighs
//   (R4: 8->5 waves/SIMD scaled dur 1.6x).
// ---------------------------------------------------------------------------
#define NCH 16
__global__ __launch_bounds__(256) void k_final(
        const float* __restrict__ en, const float* __restrict__ de,
        const float* __restrict__ tmp1, const float* __restrict__ tmp2,
        const float* __restrict__ gate_lr, float* __restrict__ out) {
    __shared__ float sde[NCH][8][36];             // 18432 B
    int t = threadIdx.x;
    int x0 = (blockIdx.x & 1) * 32, y0 = (blockIdx.x >> 1) * 4;
    int c0 = blockIdx.y * NCH;
    int b = blockIdx.z;

    const float* dbase = de + ((size_t)b * C + c0) * HW;
    for (int idx = t; idx < NCH * 288; idx += 256) {
        int c = idx / 288, rem = idx % 288;
        int row = rem / 36, col = rem % 36;
        int yy = y0 - 2 + row, xx = x0 - 2 + col;
        float v = 0.f;
        if ((unsigned)yy < (unsigned)H && (unsigned)xx < (unsigned)W)
            v = dbase[(size_t)c * HW + yy * W + xx];
        sde[c][row][col] = v;
    }

    int tx = t & 31;
    int tyr = t >> 5;                 // 0..7 ; wave = {tx 0..31} x {r 0,1}
    int ty = tyr >> 1, r = tyr & 1;
    int yl = y0 + ty, xl = x0 + tx;
    int hrow = 2 * yl + r;
    int p0 = hrow * WO + 2 * xl;      // hi px 0; hi px 1 = p0+1
    int pl = yl * W + xl;             // lo px

    // logits for the 2 hi px of this thread; softmax in-register
    float l0[25], l1[25];
    const float* t1 = tmp1 + (((size_t)b * 25) << 14) + p0;
    const float* t2 = tmp2 + (((size_t)b * 25) << 12) + pl;
    float mx0 = -1e30f, mx1 = -1e30f;
    #pragma unroll
    for (int q = 0; q < 25; q++) {
        float2 a = *(const float2*)(t1 + ((size_t)q << 14));
        float cq = t2[(size_t)q << 12];
        l0[q] = a.x + cq; l1[q] = a.y + cq;
        mx0 = fmaxf(mx0, l0[q]); mx1 = fmaxf(mx1, l1[q]);
    }
    float s0 = 0.f, s1 = 0.f;
    #pragma unroll
    for (int q = 0; q < 25; q++) {
        l0[q] = __expf(l0[q] - mx0); s0 += l0[q];
        l1[q] = __expf(l1[q] - mx1); s1 += l1[q];
    }
    float g = gate_lr[b * HW + pl];
    float gi0 = (1.f - g) / s0;       // fold softmax 1/sum into blend weight
    float gi1 = (1.f - g) / s1;
    __syncthreads();

    const float* ebase = en + ((size_t)b * C + c0) * HWO + p0;
    float* obase = out + ((size_t)b * C + c0) * HWO + p0;
    #pragma unroll 2
    for (int c = 0; c < NCH; c++) {
        float a0 = 0.f, a1 = 0.f;
        #pragma unroll
        for (int dy = 0; dy < 5; dy++) {
            #pragma unroll
            for (int dx = 0; dx < 5; dx++) {
                float v = sde[c][ty + dy][tx + dx];
                int k = dy * 5 + dx;
                a0 += l0[k] * v;
                a1 += l1[k] * v;
            }
        }
        size_t cc = (size_t)c * HWO;
        float2 e = *(const float2*)(ebase + cc);
        float2 o;
        o.x = g * e.x + gi0 * a0;
        o.y = g * e.y + gi1 * a1;
        *(float2*)(obase + cc) = o;
    }
}

extern "C" void kernel_launch(void* const* d_in, const int* in_sizes, int n_in,
                              void* d_out, int out_size, void* d_ws, size_t ws_size,
                              hipStream_t stream) {
    const float* en     = (const float*)d_in[0];
    const float* de     = (const float*)d_in[1];
    const float* w_gate = (const float*)d_in[2];
    const float* b_gate = (const float*)d_in[3];
    const float* w_cen  = (const float*)d_in[4];
    const float* b_cen  = (const float*)d_in[5];
    const float* w_cde  = (const float*)d_in[6];
    const float* w_ce   = (const float*)d_in[7];
    const float* b_ce   = (const float*)d_in[8];
    float* out = (float*)d_out;

    __bf16* wsb     = (__bf16*)d_ws;
    __bf16* wbf_cen = wsb;                   // 16384
    __bf16* wdec5   = wbf_cen + 16384;       // 20480
    __bf16* w3      = wdec5 + 20480;         // 18432
    __bf16* enc_t   = w3 + 18432;            // 4194304
    __bf16* dec_t   = enc_t + 4194304;       // 1048576
    float* wsf     = (float*)((char*)d_ws + (size_t)(16384 + 20480 + 18432
                              + 4194304 + 1048576) * 2);
    float* tmp1    = wsf;                    // 1638400
    float* tmp2    = tmp1 + 1638400;         // 409600
    float* gate_lr = tmp2 + 409600;          // 16384

    k_prep2<<<80, 256, 0, stream>>>(w_cen, w_cde, w_gate, w_ce,
                                    wbf_cen, wdec5, w3);
    k_gemm1<<<640, 256, 0, stream>>>(en, de, wbf_cen, wdec5, b_cen, b_gate,
                                     enc_t, dec_t, gate_lr);
    k_conv3m<<<1280, 256, 0, stream>>>(enc_t, dec_t, w3, b_ce, tmp1, tmp2);
    k_final<<<dim3(32, 16, 4), 256, 0, stream>>>(en, de, tmp1, tmp2,
                                                 gate_lr, out);
}